// Round 4
// baseline (5834.253 us; speedup 1.0000x reference)
//
#include <hip/hip_runtime.h>
#include <hip/hip_bf16.h>
#include <math.h>

// Problem constants
#define B_   8
#define NB_  2048
#define NS_  1024
#define Cc_  768
#define HID_ 3072
#define NP_  1024
#define NH_  6
#define HD_  128

__device__ __forceinline__ float gelu_exact(float v) {
  return 0.5f * v * (1.0f + erff(v * 0.7071067811865476f));
}

#define BLOCK_REDUCE_ADD(red, tid)                                              \
  for (int off_ = 128; off_; off_ >>= 1) {                                      \
    if ((tid) < off_) red[(tid)] += red[(tid) + off_];                          \
    __syncthreads();                                                            \
  }

// ---------------- LayerNorm (row = 768) ----------------
__global__ __launch_bounds__(256) void ln_kernel(
    const float* __restrict__ x, float* __restrict__ y,
    const float* __restrict__ w, const float* __restrict__ b) {
  __shared__ float red[256];
  int row = blockIdx.x, tid = threadIdx.x;
  const float* xr = x + (size_t)row * Cc_;
  float* yr = y + (size_t)row * Cc_;
  float v0 = xr[tid], v1 = xr[tid + 256], v2 = xr[tid + 512];
  red[tid] = v0 + v1 + v2;
  __syncthreads();
  BLOCK_REDUCE_ADD(red, tid);
  float mu = red[0] / (float)Cc_;
  __syncthreads();
  float d0 = v0 - mu, d1 = v1 - mu, d2 = v2 - mu;
  red[tid] = d0 * d0 + d1 * d1 + d2 * d2;
  __syncthreads();
  BLOCK_REDUCE_ADD(red, tid);
  float var = red[0] / (float)Cc_;
  float rs = 1.0f / sqrtf(var + 1e-5f);
  yr[tid]       = d0 * rs * w[tid]       + b[tid];
  yr[tid + 256] = d1 * rs * w[tid + 256] + b[tid + 256];
  yr[tid + 512] = d2 * rs * w[tid + 512] + b[tid + 512];
}

// ---------------- Row L2-normalize (row = 768) ----------------
__global__ __launch_bounds__(256) void rownorm_kernel(
    const float* __restrict__ x, float* __restrict__ y) {
  __shared__ float red[256];
  int row = blockIdx.x, tid = threadIdx.x;
  const float* xr = x + (size_t)row * Cc_;
  float* yr = y + (size_t)row * Cc_;
  float v0 = xr[tid], v1 = xr[tid + 256], v2 = xr[tid + 512];
  red[tid] = v0 * v0 + v1 * v1 + v2 * v2;
  __syncthreads();
  BLOCK_REDUCE_ADD(red, tid);
  float den = fmaxf(sqrtf(red[0]), 1e-12f);
  yr[tid]       = v0 / den;
  yr[tid + 256] = v1 / den;
  yr[tid + 512] = v2 / den;
}

// ---------------- 256x128 tiled f32 GEMM, 16x8 per thread ----------------
// Raises FMA per LDS-read-instruction: 6 ds_read_b128 per 128 FMA (vs 4/64).
// Per-output-element K accumulation order identical to prior rounds.
// Split-fragment layout: rows {ty*4 + 64h, h=0..3}, cols {tx*4, tx*4+64}.
// Batched via blockIdx.z: z1 = z/(d1*d2), z2 = (z/d2)%d1, z3 = z%d2.
// TRB=0: B is KxN row-major (ldb). TRB=1: B is NxK row-major (ldb).
// EPI: 0 none; 1 +bias; 2 gelu(acc+bias); 3 acc+bias+addsrc[m] (ldc layout);
//      4 scatter: row mo=perm[m], out[mo]=acc+bias+addsrc[mo]
// AGATHER: A row index = perm[m]. MDEV: effective M = *mdev (early-exit + tail).
template <int EPI, int TRB, bool AGATHER, bool MDEV>
__global__ __launch_bounds__(256, 2) void gemm256(
    const float* __restrict__ A, const float* __restrict__ Bm,
    float* __restrict__ Cm, const float* __restrict__ bias,
    const float* __restrict__ addsrc, const int* __restrict__ perm,
    const int* __restrict__ mdev,
    int M, int N, int K, int lda, int ldb, int ldc,
    int d1, int d2,
    long a_s1, long a_s2, long a_s3,
    long b_s1, long b_s2, long b_s3,
    long c_s1, long c_s2, long c_s3,
    float scale) {
  __shared__ float As[16][260];
  __shared__ float Bs[16][132];
  int z = blockIdx.z;
  int z1 = z / (d1 * d2);
  int rem = z - z1 * d1 * d2;
  int z2 = rem / d2, z3 = rem - z2 * d2;
  const float* Ab = A + (size_t)z1 * a_s1 + (size_t)z2 * a_s2 + (size_t)z3 * a_s3;
  const float* Bb = Bm + (size_t)z1 * b_s1 + (size_t)z2 * b_s2 + (size_t)z3 * b_s3;
  float* Cb = Cm + (size_t)z1 * c_s1 + (size_t)z2 * c_s2 + (size_t)z3 * c_s3;
  int Me = MDEV ? mdev[0] : M;
  int m0 = blockIdx.y * 256, n0 = blockIdx.x * 128;
  if (MDEV && m0 >= Me) return;
  int tid = threadIdx.x;
  int tx = tid & 15, ty = tid >> 4;
  float acc[16][8] = {};
  int arow = tid >> 2, akq = tid & 3;
  for (int k0 = 0; k0 < K; k0 += 16) {
    // A tile: 256 rows x 16 k, store K-major As[k][m]
#pragma unroll
    for (int h = 0; h < 4; ++h) {
      int r = arow + h * 64;
      int m = m0 + r;
      if (MDEV) m = min(m, Me - 1);
      int mg = AGATHER ? perm[m] : m;
      const float4 va = *(const float4*)&Ab[(size_t)mg * lda + k0 + akq * 4];
      As[akq * 4 + 0][r] = va.x; As[akq * 4 + 1][r] = va.y;
      As[akq * 4 + 2][r] = va.z; As[akq * 4 + 3][r] = va.w;
    }
    if (TRB == 0) {
#pragma unroll
      for (int h = 0; h < 2; ++h) {
        int idx = tid + h * 256;
        int r = idx >> 5, nq = idx & 31;
        *(float4*)&Bs[r][nq * 4] =
            *(const float4*)&Bb[(size_t)(k0 + r) * ldb + n0 + nq * 4];
      }
    } else {
#pragma unroll
      for (int h = 0; h < 2; ++h) {
        int n = arow + h * 64;
        const float4 vb = *(const float4*)&Bb[(size_t)(n0 + n) * ldb + k0 + akq * 4];
        Bs[akq * 4 + 0][n] = vb.x; Bs[akq * 4 + 1][n] = vb.y;
        Bs[akq * 4 + 2][n] = vb.z; Bs[akq * 4 + 3][n] = vb.w;
      }
    }
    __syncthreads();
#pragma unroll
    for (int kk = 0; kk < 16; ++kk) {
      float a[16], b[8];
      *(float4*)&a[0]  = *(const float4*)&As[kk][ty * 4];
      *(float4*)&a[4]  = *(const float4*)&As[kk][ty * 4 + 64];
      *(float4*)&a[8]  = *(const float4*)&As[kk][ty * 4 + 128];
      *(float4*)&a[12] = *(const float4*)&As[kk][ty * 4 + 192];
      *(float4*)&b[0] = *(const float4*)&Bs[kk][tx * 4];
      *(float4*)&b[4] = *(const float4*)&Bs[kk][tx * 4 + 64];
#pragma unroll
      for (int i = 0; i < 16; ++i)
#pragma unroll
        for (int j = 0; j < 8; ++j)
          acc[i][j] = fmaf(a[i], b[j], acc[i][j]);
    }
    __syncthreads();
  }
#pragma unroll
  for (int i = 0; i < 16; ++i) {
    int m = m0 + ty * 4 + (i & 3) + ((i >> 2) << 6);
    if (!MDEV || m < Me) {
      int mo = (EPI == 4) ? perm[m] : m;
      int n = n0 + tx * 4;
      float v[8];
#pragma unroll
      for (int j = 0; j < 8; ++j) {
        int nj = (j < 4) ? (n + j) : (n + 64 + j - 4);
        v[j] = acc[i][j] * scale;
        if (EPI >= 1) v[j] += bias[nj];
        if (EPI == 2) v[j] = gelu_exact(v[j]);
        if (EPI == 3 || EPI == 4) v[j] += addsrc[(size_t)mo * ldc + nj];
      }
      float* cp = &Cb[(size_t)mo * ldc + n];
      *(float4*)cp = make_float4(v[0], v[1], v[2], v[3]);
      *(float4*)(cp + 64) = make_float4(v[4], v[5], v[6], v[7]);
    }
  }
}

// ---------------- PV split-K reduce: ctx[m][h*128+n] = sum_ks part ---------
__global__ __launch_bounds__(256) void pv_reduce(
    const float* __restrict__ part, float* __restrict__ ctx) {
  int i = blockIdx.x * 256 + threadIdx.x;  // < 6*1024*128
  int n = i & 127, m = (i >> 7) & 1023, h = i >> 17;
  float s = 0.f;
#pragma unroll
  for (int ks = 0; ks < 16; ++ks)
    s += part[(size_t)(ks * 6 + h) * 131072 + m * 128 + n];
  ctx[(size_t)m * 768 + h * 128 + n] = s;
}

// ---------------- Softmax over row of length L = EPT*256 ----------------
template <int EPT, bool MASK>
__global__ __launch_bounds__(256) void softmax_kernel(
    float* __restrict__ s, const float* __restrict__ maskf) {
  __shared__ float red[256];
  int row = blockIdx.x, tid = threadIdx.x;
  float* sr = s + (size_t)row * (EPT * 256);
  const float* mb = MASK ? (maskf + (size_t)(row / 512) * 512) : nullptr;
  float v[EPT];
  float m = -3.0e38f;
#pragma unroll
  for (int t = 0; t < EPT; ++t) {
    int j = tid + (t << 8);
    float xv = sr[j];
    if (MASK) xv += (mb[j] != 0.0f) ? 0.0f : -1e9f;
    v[t] = xv;
    m = fmaxf(m, xv);
  }
  red[tid] = m;
  __syncthreads();
  for (int off = 128; off; off >>= 1) {
    if (tid < off) red[tid] = fmaxf(red[tid], red[tid + off]);
    __syncthreads();
  }
  m = red[0];
  __syncthreads();
  float ssum = 0.f;
#pragma unroll
  for (int t = 0; t < EPT; ++t) {
    v[t] = expf(v[t] - m);
    ssum += v[t];
  }
  red[tid] = ssum;
  __syncthreads();
  BLOCK_REDUCE_ADD(red, tid);
  float tot = red[0];
#pragma unroll
  for (int t = 0; t < EPT; ++t) sr[tid + (t << 8)] = v[t] / tot;
}

// ---------------- MoE permutation build (order-free compaction) ------------
__global__ __launch_bounds__(256) void build_perm(
    const int* __restrict__ tt, int* __restrict__ perm0,
    int* __restrict__ perm1, int* __restrict__ cnt) {
  int r = blockIdx.x * 256 + threadIdx.x;  // < 8192
  int t = tt[r];
  if (t == 0) { int p = atomicAdd(&cnt[0], 1); perm0[p] = r; }
  else        { int p = atomicAdd(&cnt[1], 1); perm1[p] = r; }
}

// ---------------- Token gather ----------------
__global__ __launch_bounds__(256) void gather_kernel(
    const float* __restrict__ xb, const int* __restrict__ bidx,
    float* __restrict__ tokens, float* __restrict__ maskf) {
  size_t idx = (size_t)blockIdx.x * 256 + threadIdx.x;  // < 8*512*768
  int c = (int)(idx % Cc_);
  int i = (int)((idx / Cc_) % 512);
  int b = (int)(idx / ((size_t)Cc_ * 512));
  int id = bidx[b * NP_ + i];
  bool m = id >= 0;
  int idc = m ? id : 0;
  tokens[idx] = m ? xb[((size_t)b * NB_ + idc) * Cc_ + c] : 0.0f;
  if (c == 0) maskf[b * 512 + i] = m ? 1.0f : 0.0f;
}

// ---------------- ksum -> kernel (one block per batch) ----------------
__global__ __launch_bounds__(256) void kernel_kernel(
    const float* __restrict__ agg, const float* __restrict__ maskf,
    float* __restrict__ kern, float* __restrict__ hasf) {
  __shared__ float red[256];
  __shared__ float ks[Cc_];
  __shared__ float s_cnt;
  int b = blockIdx.x, tid = threadIdx.x;
  const float* mb = maskf + b * 512;
  red[tid] = mb[tid] + mb[tid + 256];
  __syncthreads();
  BLOCK_REDUCE_ADD(red, tid);
  if (tid == 0) s_cnt = red[0];
  __syncthreads();
  float cnt = s_cnt;
  float dc = fmaxf(cnt, 1.0f);
  const float* ab = agg + (size_t)b * 512 * Cc_;
#pragma unroll
  for (int t = 0; t < 3; ++t) {
    int cc = tid + t * 256;
    float s = 0.f;
    for (int i = 0; i < 512; ++i) s = fmaf(ab[(size_t)i * Cc_ + cc], mb[i], s);
    ks[cc] = s / dc;
  }
  __syncthreads();
  float s2 = 0.f;
#pragma unroll
  for (int t = 0; t < 3; ++t) {
    float q = ks[tid + t * 256];
    s2 = fmaf(q, q, s2);
  }
  red[tid] = s2;
  __syncthreads();
  BLOCK_REDUCE_ADD(red, tid);
  float den = fmaxf(sqrtf(red[0]), 1e-12f);
  bool has = cnt > 0.5f;
#pragma unroll
  for (int t = 0; t < 3; ++t) {
    int cc = tid + t * 256;
    kern[(size_t)b * Cc_ + cc] = has ? (ks[cc] / den) : 0.0f;
  }
  if (tid == 0) hasf[b] = has ? 1.0f : 0.0f;
}

// ---------------- pos ----------------
__global__ __launch_bounds__(256) void pos_kernel(
    const float* __restrict__ xnorm, const float* __restrict__ kern,
    const float* __restrict__ hasf, float* __restrict__ pos) {
  __shared__ float red[256];
  int row = blockIdx.x, tid = threadIdx.x;
  int b = row >> 10;
  const float* xr = xnorm + (size_t)row * Cc_;
  const float* kr = kern + (size_t)b * Cc_;
  float s = xr[tid] * kr[tid];
  s = fmaf(xr[tid + 256], kr[tid + 256], s);
  s = fmaf(xr[tid + 512], kr[tid + 512], s);
  red[tid] = s;
  __syncthreads();
  BLOCK_REDUCE_ADD(red, tid);
  if (tid == 0) pos[row] = (hasf[b] > 0.5f) ? (red[0] + 1.0f) * 0.5f : 0.0f;
}

// ---------------- per-batch top-128 ----------------
__global__ __launch_bounds__(256) void topk_kernel(
    const float* __restrict__ pos, float* __restrict__ sel,
    float* __restrict__ topi) {
  __shared__ float vals[NS_];
  __shared__ float rv[256];
  __shared__ int ri[256];
  __shared__ int s_vk;
  int b = blockIdx.x, tid = threadIdx.x;
  const float* pr = pos + (size_t)b * NS_;
  int c65 = 0;
#pragma unroll
  for (int t = 0; t < 4; ++t) {
    float v = pr[tid + (t << 8)];
    vals[tid + (t << 8)] = v;
    if (v > 0.65f) ++c65;
  }
  ri[tid] = c65;
  __syncthreads();
  for (int off = 128; off; off >>= 1) {
    if (tid < off) ri[tid] += ri[tid + off];
    __syncthreads();
  }
  if (tid == 0) {
    int vk = ri[0] > 118 ? ri[0] : 118;
    s_vk = vk > 128 ? 128 : vk;
  }
  __syncthreads();
  int vk = s_vk;
  for (int r = 0; r < 128; ++r) {
    float bv = -3.0e38f;
    int bi = 0x7fffffff;
#pragma unroll
    for (int t = 0; t < 4; ++t) {
      int i = tid + (t << 8);
      float v = vals[i];
      if (v > bv) { bv = v; bi = i; }
    }
    rv[tid] = bv; ri[tid] = bi;
    __syncthreads();
    for (int off = 128; off; off >>= 1) {
      if (tid < off) {
        float ov = rv[tid + off]; int oi = ri[tid + off];
        if (ov > rv[tid] || (ov == rv[tid] && oi < ri[tid])) {
          rv[tid] = ov; ri[tid] = oi;
        }
      }
      __syncthreads();
    }
    if (tid == 0) {
      int wi = ri[0]; float wv = rv[0];
      topi[(size_t)b * 128 + r] = (float)wi;
      if (r < vk && wv > 0.0f) sel[((size_t)b * 128 + r) * NS_ + wi] = 1.0f;
      vals[wi] = -3.0e38f;
    }
    __syncthreads();
  }
}

extern "C" void kernel_launch(void* const* d_in, const int* in_sizes, int n_in,
                              void* d_out, int out_size, void* d_ws, size_t ws_size,
                              hipStream_t stream) {
  (void)in_sizes; (void)n_in; (void)out_size; (void)ws_size;
  const float* x_b = (const float*)d_in[0];
  const float* x_s = (const float*)d_in[1];
  const int* token_types = (const int*)d_in[2];
  const int* base_idxs = (const int*)d_in[3];
  const float* ln1_w = (const float*)d_in[4];
  const float* ln1_b = (const float*)d_in[5];
  const float* ln2_w = (const float*)d_in[6];
  const float* ln2_b = (const float*)d_in[7];
  const float* ln3_w = (const float*)d_in[8];
  const float* ln3_b = (const float*)d_in[9];
  const float* Wq = (const float*)d_in[10];
  const float* Wkv = (const float*)d_in[11];
  const float* es_w1 = (const float*)d_in[12];
  const float* es_b1 = (const float*)d_in[13];
  const float* es_w2 = (const float*)d_in[14];
  const float* es_b2 = (const float*)d_in[15];
  const float* el_w1 = (const float*)d_in[16];
  const float* el_b1 = (const float*)d_in[17];
  const float* el_w2 = (const float*)d_in[18];
  const float* el_b2 = (const float*)d_in[19];
  const float* mlp_w1 = (const float*)d_in[20];
  const float* mlp_b1 = (const float*)d_in[21];
  const float* mlp_w2 = (const float*)d_in[22];
  const float* mlp_b2 = (const float*)d_in[23];

  float* out = (float*)d_out;
  float* sel_out  = out;                 // 8*128*1024
  float* topi_out = out + 1048576;       // 1024
  float* pos_out  = out + 1049600;       // 8192
  float* x_out    = out + 1057792;       // 6291456
  float* kern_out = out + 7349248;       // 6144

  // workspace layout (floats), ~252 MB total
  float* w = (float*)d_ws;
  float* ws0 = w;               // 6291456  : xs_n -> ctx -> x_ln
  float* ws1 = w + 6291456;     // 6291456  : q -> x_norm
  float* ws2 = w + 12582912;    // 25165824 : kv -> {tokens, aw, agg}
  float* ws3 = w + 37748736;    // 25165824 : xb_n -> {scores|partial} -> h
  float* tokens = ws2;                    // 3145728
  float* aw     = ws2 + 3145728;          // 2097152
  float* agg    = ws2 + 5242880;          // 3145728
  float* scores = ws3;                    // 12582912 (1 batch: 6*1024*2048)
  float* part   = ws3 + 12582912;         // 12582912 (16*6*1024*128)
  float* small  = w + 62914560;
  float* maskf  = small;                  // 4096
  float* hasf   = small + 4096;           // 8
  int* cnt      = (int*)(small + 4104);   // 2
  int* perm0    = (int*)(small + 4106);   // 8192
  int* perm1    = (int*)(small + 12298);  // 8192

  const long NSC = (long)NS_ * Cc_;        // 786432
  const long NB2C = (long)NB_ * 2 * Cc_;   // 3145728
  const long SNB = (long)NS_ * NB_;        // 2097152
  const float qk_scale = 0.08838834764831845f;   // 1/sqrt(128)
  const float sc_scale = 0.036084391824351615f;  // 1/sqrt(768)

  hipMemsetAsync(sel_out, 0, (size_t)1048576 * sizeof(float), stream);
  hipMemsetAsync(cnt, 0, 2 * sizeof(int), stream);

  ln_kernel<<<B_ * NS_, 256, 0, stream>>>(x_s, ws0, ln1_w, ln1_b);
  ln_kernel<<<B_ * NB_, 256, 0, stream>>>(x_b, ws3, ln2_w, ln2_b);
  build_perm<<<32, 256, 0, stream>>>(token_types, perm0, perm1, cnt);

  // q = xs_n @ Wq (8192x768x768)
  gemm256<0, 0, false, false><<<dim3(6, 32, 1), 256, 0, stream>>>(
      ws0, Wq, ws1, nullptr, nullptr, nullptr, nullptr,
      8192, 768, 768, 768, 768, 768,
      1, 1, 0, 0, 0, 0, 0, 0, 0, 0, 0, 1.0f);
  // kv = xb_n @ Wkv (16384x1536x768)
  gemm256<0, 0, false, false><<<dim3(12, 64, 1), 256, 0, stream>>>(
      ws3, Wkv, ws2, nullptr, nullptr, nullptr, nullptr,
      16384, 1536, 768, 768, 1536, 1536,
      1, 1, 0, 0, 0, 0, 0, 0, 0, 0, 0, 1.0f);

  // attention: 1 batch per chunk; scores + 16-way split-K PV partials in ws3
  for (int b = 0; b < B_; ++b) {
    const float* qb = ws1 + (size_t)b * NSC;
    const float* kb = ws2 + (size_t)b * NB2C;
    const float* vb = kb + Cc_;
    // QK^T: z = h (6): A off h*128, B off h*128, C off h*SNB
    gemm256<0, 1, false, false><<<dim3(16, 4, 6), 256, 0, stream>>>(
        qb, kb, scores, nullptr, nullptr, nullptr, nullptr,
        1024, 2048, 128, 768, 1536, 2048,
        1, 1, 128, 0, 0, 128, 0, 0, SNB, 0, 0, qk_scale);
    softmax_kernel<8, false><<<6 * 1024, 256, 0, stream>>>(scores, nullptr);
    // PV split-K: z = h*16 + ks (d1=6, d2=16)
    gemm256<0, 0, false, false><<<dim3(1, 4, 96), 256, 0, stream>>>(
        scores, vb, part, nullptr, nullptr, nullptr, nullptr,
        1024, 128, 128, 2048, 1536, 128,
        6, 16, 0, SNB, 128, 0, 128, 128 * 1536, 0, 131072, 786432, 1.0f);
    pv_reduce<<<3072, 256, 0, stream>>>(part, ws0 + (size_t)b * NSC);
  }

  // MoE: per-row single expert. e0 rows=perm0[0..cnt0), e1 rows=perm1
  gemm256<2, 0, true, true><<<dim3(24, 32, 1), 256, 0, stream>>>(
      ws0, es_w1, ws3, es_b1, nullptr, perm0, cnt,
      8192, 3072, 768, 768, 3072, 3072,
      1, 1, 0, 0, 0, 0, 0, 0, 0, 0, 0, 1.0f);
  gemm256<4, 0, false, true><<<dim3(6, 32, 1), 256, 0, stream>>>(
      ws3, es_w2, x_out, es_b2, x_s, perm0, cnt,
      8192, 768, 3072, 3072, 768, 768,
      1, 1, 0, 0, 0, 0, 0, 0, 0, 0, 0, 1.0f);
  gemm256<2, 0, true, true><<<dim3(24, 32, 1), 256, 0, stream>>>(
      ws0, el_w1, ws3, el_b1, nullptr, perm1, cnt + 1,
      8192, 3072, 768, 768, 3072, 3072,
      1, 1, 0, 0, 0, 0, 0, 0, 0, 0, 0, 1.0f);
  gemm256<4, 0, false, true><<<dim3(6, 32, 1), 256, 0, stream>>>(
      ws3, el_w2, x_out, el_b2, x_s, perm1, cnt + 1,
      8192, 768, 3072, 3072, 768, 768,
      1, 1, 0, 0, 0, 0, 0, 0, 0, 0, 0, 1.0f);

  // MLP with residual
  ln_kernel<<<B_ * NS_, 256, 0, stream>>>(x_out, ws0, ln3_w, ln3_b);
  gemm256<2, 0, false, false><<<dim3(24, 32, 1), 256, 0, stream>>>(
      ws0, mlp_w1, ws3, mlp_b1, nullptr, nullptr, nullptr,
      8192, 3072, 768, 768, 3072, 3072,
      1, 1, 0, 0, 0, 0, 0, 0, 0, 0, 0, 1.0f);
  gemm256<3, 0, false, false><<<dim3(6, 32, 1), 256, 0, stream>>>(
      ws3, mlp_w2, x_out, mlp_b2, x_out, nullptr, nullptr,
      8192, 768, 3072, 3072, 768, 768,
      1, 1, 0, 0, 0, 0, 0, 0, 0, 0, 0, 1.0f);

  // x_norm
  rownorm_kernel<<<B_ * NS_, 256, 0, stream>>>(x_out, ws1);

  // token gather + mask
  gather_kernel<<<12288, 256, 0, stream>>>(x_b, base_idxs, tokens, maskf);

  // kernel-attention
  gemm256<0, 1, false, false><<<dim3(4, 2, 8), 256, 0, stream>>>(
      tokens, tokens, aw, nullptr, nullptr, nullptr, nullptr,
      512, 512, 768, 768, 768, 512,
      1, 1, 393216, 0, 0, 393216, 0, 0, 262144, 0, 0, sc_scale);
  softmax_kernel<2, true><<<8 * 512, 256, 0, stream>>>(aw, maskf);
  gemm256<0, 0, false, false><<<dim3(6, 2, 8), 256, 0, stream>>>(
      aw, tokens, agg, nullptr, nullptr, nullptr, nullptr,
      512, 768, 512, 512, 768, 768,
      1, 1, 262144, 0, 0, 393216, 0, 0, 393216, 0, 0, 1.0f);

  kernel_kernel<<<8, 256, 0, stream>>>(agg, maskf, kern_out, hasf);
  pos_kernel<<<B_ * NS_, 256, 0, stream>>>(ws1, kern_out, hasf, pos_out);
  topk_kernel<<<8, 256, 0, stream>>>(pos_out, sel_out, topi_out);
}

// Round 5
// 4340.494 us; speedup vs baseline: 1.3441x; 1.3441x over previous
//
#include <hip/hip_runtime.h>
#include <hip/hip_bf16.h>
#include <math.h>

// Problem constants
#define B_   8
#define NB_  2048
#define NS_  1024
#define Cc_  768
#define HID_ 3072
#define NP_  1024
#define NH_  6
#define HD_  128

__device__ __forceinline__ float gelu_exact(float v) {
  return 0.5f * v * (1.0f + erff(v * 0.7071067811865476f));
}

#define BLOCK_REDUCE_ADD(red, tid)                                              \
  for (int off_ = 128; off_; off_ >>= 1) {                                      \
    if ((tid) < off_) red[(tid)] += red[(tid) + off_];                          \
    __syncthreads();                                                            \
  }

// ---------------- LayerNorm (row = 768) ----------------
__global__ __launch_bounds__(256) void ln_kernel(
    const float* __restrict__ x, float* __restrict__ y,
    const float* __restrict__ w, const float* __restrict__ b) {
  __shared__ float red[256];
  int row = blockIdx.x, tid = threadIdx.x;
  const float* xr = x + (size_t)row * Cc_;
  float* yr = y + (size_t)row * Cc_;
  float v0 = xr[tid], v1 = xr[tid + 256], v2 = xr[tid + 512];
  red[tid] = v0 + v1 + v2;
  __syncthreads();
  BLOCK_REDUCE_ADD(red, tid);
  float mu = red[0] / (float)Cc_;
  __syncthreads();
  float d0 = v0 - mu, d1 = v1 - mu, d2 = v2 - mu;
  red[tid] = d0 * d0 + d1 * d1 + d2 * d2;
  __syncthreads();
  BLOCK_REDUCE_ADD(red, tid);
  float var = red[0] / (float)Cc_;
  float rs = 1.0f / sqrtf(var + 1e-5f);
  yr[tid]       = d0 * rs * w[tid]       + b[tid];
  yr[tid + 256] = d1 * rs * w[tid + 256] + b[tid + 256];
  yr[tid + 512] = d2 * rs * w[tid + 512] + b[tid + 512];
}

// ---------------- Row L2-normalize (row = 768) ----------------
__global__ __launch_bounds__(256) void rownorm_kernel(
    const float* __restrict__ x, float* __restrict__ y) {
  __shared__ float red[256];
  int row = blockIdx.x, tid = threadIdx.x;
  const float* xr = x + (size_t)row * Cc_;
  float* yr = y + (size_t)row * Cc_;
  float v0 = xr[tid], v1 = xr[tid + 256], v2 = xr[tid + 512];
  red[tid] = v0 * v0 + v1 * v1 + v2 * v2;
  __syncthreads();
  BLOCK_REDUCE_ADD(red, tid);
  float den = fmaxf(sqrtf(red[0]), 1e-12f);
  yr[tid]       = v0 / den;
  yr[tid + 256] = v1 / den;
  yr[tid + 512] = v2 / den;
}

// ---------------- 128x128 tiled f32 GEMM, 8x8/thread, reg-prefetch dbuf ----
// Pipeline per k-tile: ds_write(regs, buf[t&1]) -> issue global loads(t+1)
// -> s_waitcnt lgkmcnt(0) -> raw s_barrier -> FMA on buf[t&1].
// Loads stay in flight across the barrier (no vmcnt drain); consumed by next
// ds_write after ~2048 cyc of FMA. One barrier per k-tile.
// Per-output-element K accumulation order identical to prior rounds.
// Split-fragment layout: rows {ty*4, 64+ty*4}, cols {tx*4, 64+tx*4}.
// Batched via blockIdx.z: z1 = z/(d1*d2), z2 = (z/d2)%d1, z3 = z%d2.
// TRB=0: B is KxN row-major (ldb). TRB=1: B is NxK row-major (ldb).
// EPI: 0 none; 1 +bias; 2 gelu(acc+bias); 3 acc+bias+addsrc[m] (ldc layout);
//      4 scatter: row mo=perm[m], out[mo]=acc+bias+addsrc[mo]
// AGATHER: A row index = perm[m]. MDEV: effective M = *mdev (early-exit + tail).
template <int EPI, int TRB, bool AGATHER, bool MDEV>
__global__ __launch_bounds__(256) void gemm128(
    const float* __restrict__ A, const float* __restrict__ Bm,
    float* __restrict__ Cm, const float* __restrict__ bias,
    const float* __restrict__ addsrc, const int* __restrict__ perm,
    const int* __restrict__ mdev,
    int M, int N, int K, int lda, int ldb, int ldc,
    int d1, int d2,
    long a_s1, long a_s2, long a_s3,
    long b_s1, long b_s2, long b_s3,
    long c_s1, long c_s2, long c_s3,
    float scale) {
  __shared__ float As[2][16][132];
  __shared__ float Bs[2][16][132];
  int z = blockIdx.z;
  int z1 = z / (d1 * d2);
  int rem = z - z1 * d1 * d2;
  int z2 = rem / d2, z3 = rem - z2 * d2;
  const float* Ab = A + (size_t)z1 * a_s1 + (size_t)z2 * a_s2 + (size_t)z3 * a_s3;
  const float* Bb = Bm + (size_t)z1 * b_s1 + (size_t)z2 * b_s2 + (size_t)z3 * b_s3;
  float* Cb = Cm + (size_t)z1 * c_s1 + (size_t)z2 * c_s2 + (size_t)z3 * c_s3;
  int Me = MDEV ? mdev[0] : M;
  int m0 = blockIdx.y * 128, n0 = blockIdx.x * 128;
  if (MDEV && m0 >= Me) return;
  int tid = threadIdx.x;
  int tx = tid & 15, ty = tid >> 4;
  int arow = tid >> 2, akq = tid & 3;

  // k-invariant global source pointers
  int ma0 = m0 + arow, ma1 = m0 + arow + 64;
  if (MDEV) { ma0 = min(ma0, Me - 1); ma1 = min(ma1, Me - 1); }
  if (AGATHER) { ma0 = perm[ma0]; ma1 = perm[ma1]; }
  const float* Ap0 = Ab + (size_t)ma0 * lda + akq * 4;
  const float* Ap1 = Ab + (size_t)ma1 * lda + akq * 4;
  const float* Bp0;
  const float* Bp1;
  int bw_r0 = 0, bw_c0 = 0, bw_r1 = 0;
  if (TRB == 0) {
    bw_r0 = tid >> 5; bw_c0 = (tid & 31) * 4; bw_r1 = bw_r0 + 8;
    Bp0 = Bb + (size_t)bw_r0 * ldb + n0 + bw_c0;
    Bp1 = Bb + (size_t)bw_r1 * ldb + n0 + bw_c0;
  } else {
    Bp0 = Bb + (size_t)(n0 + arow) * ldb + akq * 4;
    Bp1 = Bb + (size_t)(n0 + arow + 64) * ldb + akq * 4;
  }

  // prologue: tile 0 -> regs
  float4 pa0 = *(const float4*)Ap0;
  float4 pa1 = *(const float4*)Ap1;
  float4 pb0 = *(const float4*)Bp0;
  float4 pb1 = *(const float4*)Bp1;

  float acc[8][8] = {};
  int nt = K >> 4;
  for (int t = 0; t < nt; ++t) {
    int cur = t & 1;
    // stage tile t into LDS
    As[cur][akq * 4 + 0][arow] = pa0.x; As[cur][akq * 4 + 1][arow] = pa0.y;
    As[cur][akq * 4 + 2][arow] = pa0.z; As[cur][akq * 4 + 3][arow] = pa0.w;
    As[cur][akq * 4 + 0][arow + 64] = pa1.x; As[cur][akq * 4 + 1][arow + 64] = pa1.y;
    As[cur][akq * 4 + 2][arow + 64] = pa1.z; As[cur][akq * 4 + 3][arow + 64] = pa1.w;
    if (TRB == 0) {
      *(float4*)&Bs[cur][bw_r0][bw_c0] = pb0;
      *(float4*)&Bs[cur][bw_r1][bw_c0] = pb1;
    } else {
      Bs[cur][akq * 4 + 0][arow] = pb0.x; Bs[cur][akq * 4 + 1][arow] = pb0.y;
      Bs[cur][akq * 4 + 2][arow] = pb0.z; Bs[cur][akq * 4 + 3][arow] = pb0.w;
      Bs[cur][akq * 4 + 0][arow + 64] = pb1.x; Bs[cur][akq * 4 + 1][arow + 64] = pb1.y;
      Bs[cur][akq * 4 + 2][arow + 64] = pb1.z; Bs[cur][akq * 4 + 3][arow + 64] = pb1.w;
    }
    // issue next-tile loads (stay in flight across the barrier)
    if (t + 1 < nt) {
      int kn = (t + 1) << 4;
      pa0 = *(const float4*)&Ap0[kn];
      pa1 = *(const float4*)&Ap1[kn];
      if (TRB == 0) {
        pb0 = *(const float4*)&Bp0[(size_t)kn * ldb];
        pb1 = *(const float4*)&Bp1[(size_t)kn * ldb];
      } else {
        pb0 = *(const float4*)&Bp0[kn];
        pb1 = *(const float4*)&Bp1[kn];
      }
    }
    // my LDS writes done -> barrier (raw: no vmcnt drain)
    asm volatile("s_waitcnt lgkmcnt(0)" ::: "memory");
    __builtin_amdgcn_s_barrier();
#pragma unroll
    for (int kk = 0; kk < 16; ++kk) {
      float a[8], b[8];
      *(float4*)&a[0] = *(const float4*)&As[cur][kk][ty * 4];
      *(float4*)&a[4] = *(const float4*)&As[cur][kk][ty * 4 + 64];
      *(float4*)&b[0] = *(const float4*)&Bs[cur][kk][tx * 4];
      *(float4*)&b[4] = *(const float4*)&Bs[cur][kk][tx * 4 + 64];
#pragma unroll
      for (int i = 0; i < 8; ++i)
#pragma unroll
        for (int j = 0; j < 8; ++j)
          acc[i][j] = fmaf(a[i], b[j], acc[i][j]);
    }
  }
#pragma unroll
  for (int i = 0; i < 8; ++i) {
    int m = m0 + ((i < 4) ? (ty * 4 + i) : (64 + ty * 4 + i - 4));
    if (!MDEV || m < Me) {
      int mo = (EPI == 4) ? perm[m] : m;
      int n = n0 + tx * 4;
      float v[8];
#pragma unroll
      for (int j = 0; j < 8; ++j) {
        int nj = (j < 4) ? (n + j) : (n + 64 + j - 4);
        v[j] = acc[i][j] * scale;
        if (EPI >= 1) v[j] += bias[nj];
        if (EPI == 2) v[j] = gelu_exact(v[j]);
        if (EPI == 3 || EPI == 4) v[j] += addsrc[(size_t)mo * ldc + nj];
      }
      float* cp = &Cb[(size_t)mo * ldc + n];
      *(float4*)cp = make_float4(v[0], v[1], v[2], v[3]);
      *(float4*)(cp + 64) = make_float4(v[4], v[5], v[6], v[7]);
    }
  }
}

// ---------------- PV split-K reduce: ctx[m][h*128+n] = sum_ks part ---------
__global__ __launch_bounds__(256) void pv_reduce(
    const float* __restrict__ part, float* __restrict__ ctx) {
  int i = blockIdx.x * 256 + threadIdx.x;  // < 6*1024*128
  int n = i & 127, m = (i >> 7) & 1023, h = i >> 17;
  float s = 0.f;
#pragma unroll
  for (int ks = 0; ks < 16; ++ks)
    s += part[(size_t)(ks * 6 + h) * 131072 + m * 128 + n];
  ctx[(size_t)m * 768 + h * 128 + n] = s;
}

// ---------------- Softmax over row of length L = EPT*256 ----------------
template <int EPT, bool MASK>
__global__ __launch_bounds__(256) void softmax_kernel(
    float* __restrict__ s, const float* __restrict__ maskf) {
  __shared__ float red[256];
  int row = blockIdx.x, tid = threadIdx.x;
  float* sr = s + (size_t)row * (EPT * 256);
  const float* mb = MASK ? (maskf + (size_t)(row / 512) * 512) : nullptr;
  float v[EPT];
  float m = -3.0e38f;
#pragma unroll
  for (int t = 0; t < EPT; ++t) {
    int j = tid + (t << 8);
    float xv = sr[j];
    if (MASK) xv += (mb[j] != 0.0f) ? 0.0f : -1e9f;
    v[t] = xv;
    m = fmaxf(m, xv);
  }
  red[tid] = m;
  __syncthreads();
  for (int off = 128; off; off >>= 1) {
    if (tid < off) red[tid] = fmaxf(red[tid], red[tid + off]);
    __syncthreads();
  }
  m = red[0];
  __syncthreads();
  float ssum = 0.f;
#pragma unroll
  for (int t = 0; t < EPT; ++t) {
    v[t] = expf(v[t] - m);
    ssum += v[t];
  }
  red[tid] = ssum;
  __syncthreads();
  BLOCK_REDUCE_ADD(red, tid);
  float tot = red[0];
#pragma unroll
  for (int t = 0; t < EPT; ++t) sr[tid + (t << 8)] = v[t] / tot;
}

// ---------------- MoE permutation build (order-free compaction) ------------
__global__ __launch_bounds__(256) void build_perm(
    const int* __restrict__ tt, int* __restrict__ perm0,
    int* __restrict__ perm1, int* __restrict__ cnt) {
  int r = blockIdx.x * 256 + threadIdx.x;  // < 8192
  int t = tt[r];
  if (t == 0) { int p = atomicAdd(&cnt[0], 1); perm0[p] = r; }
  else        { int p = atomicAdd(&cnt[1], 1); perm1[p] = r; }
}

// ---------------- Token gather ----------------
__global__ __launch_bounds__(256) void gather_kernel(
    const float* __restrict__ xb, const int* __restrict__ bidx,
    float* __restrict__ tokens, float* __restrict__ maskf) {
  size_t idx = (size_t)blockIdx.x * 256 + threadIdx.x;  // < 8*512*768
  int c = (int)(idx % Cc_);
  int i = (int)((idx / Cc_) % 512);
  int b = (int)(idx / ((size_t)Cc_ * 512));
  int id = bidx[b * NP_ + i];
  bool m = id >= 0;
  int idc = m ? id : 0;
  tokens[idx] = m ? xb[((size_t)b * NB_ + idc) * Cc_ + c] : 0.0f;
  if (c == 0) maskf[b * 512 + i] = m ? 1.0f : 0.0f;
}

// ---------------- ksum -> kernel (one block per batch) ----------------
__global__ __launch_bounds__(256) void kernel_kernel(
    const float* __restrict__ agg, const float* __restrict__ maskf,
    float* __restrict__ kern, float* __restrict__ hasf) {
  __shared__ float red[256];
  __shared__ float ks[Cc_];
  __shared__ float s_cnt;
  int b = blockIdx.x, tid = threadIdx.x;
  const float* mb = maskf + b * 512;
  red[tid] = mb[tid] + mb[tid + 256];
  __syncthreads();
  BLOCK_REDUCE_ADD(red, tid);
  if (tid == 0) s_cnt = red[0];
  __syncthreads();
  float cnt = s_cnt;
  float dc = fmaxf(cnt, 1.0f);
  const float* ab = agg + (size_t)b * 512 * Cc_;
#pragma unroll
  for (int t = 0; t < 3; ++t) {
    int cc = tid + t * 256;
    float s = 0.f;
    for (int i = 0; i < 512; ++i) s = fmaf(ab[(size_t)i * Cc_ + cc], mb[i], s);
    ks[cc] = s / dc;
  }
  __syncthreads();
  float s2 = 0.f;
#pragma unroll
  for (int t = 0; t < 3; ++t) {
    float q = ks[tid + t * 256];
    s2 = fmaf(q, q, s2);
  }
  red[tid] = s2;
  __syncthreads();
  BLOCK_REDUCE_ADD(red, tid);
  float den = fmaxf(sqrtf(red[0]), 1e-12f);
  bool has = cnt > 0.5f;
#pragma unroll
  for (int t = 0; t < 3; ++t) {
    int cc = tid + t * 256;
    kern[(size_t)b * Cc_ + cc] = has ? (ks[cc] / den) : 0.0f;
  }
  if (tid == 0) hasf[b] = has ? 1.0f : 0.0f;
}

// ---------------- pos ----------------
__global__ __launch_bounds__(256) void pos_kernel(
    const float* __restrict__ xnorm, const float* __restrict__ kern,
    const float* __restrict__ hasf, float* __restrict__ pos) {
  __shared__ float red[256];
  int row = blockIdx.x, tid = threadIdx.x;
  int b = row >> 10;
  const float* xr = xnorm + (size_t)row * Cc_;
  const float* kr = kern + (size_t)b * Cc_;
  float s = xr[tid] * kr[tid];
  s = fmaf(xr[tid + 256], kr[tid + 256], s);
  s = fmaf(xr[tid + 512], kr[tid + 512], s);
  red[tid] = s;
  __syncthreads();
  BLOCK_REDUCE_ADD(red, tid);
  if (tid == 0) pos[row] = (hasf[b] > 0.5f) ? (red[0] + 1.0f) * 0.5f : 0.0f;
}

// ---------------- per-batch top-128 ----------------
__global__ __launch_bounds__(256) void topk_kernel(
    const float* __restrict__ pos, float* __restrict__ sel,
    float* __restrict__ topi) {
  __shared__ float vals[NS_];
  __shared__ float rv[256];
  __shared__ int ri[256];
  __shared__ int s_vk;
  int b = blockIdx.x, tid = threadIdx.x;
  const float* pr = pos + (size_t)b * NS_;
  int c65 = 0;
#pragma unroll
  for (int t = 0; t < 4; ++t) {
    float v = pr[tid + (t << 8)];
    vals[tid + (t << 8)] = v;
    if (v > 0.65f) ++c65;
  }
  ri[tid] = c65;
  __syncthreads();
  for (int off = 128; off; off >>= 1) {
    if (tid < off) ri[tid] += ri[tid + off];
    __syncthreads();
  }
  if (tid == 0) {
    int vk = ri[0] > 118 ? ri[0] : 118;
    s_vk = vk > 128 ? 128 : vk;
  }
  __syncthreads();
  int vk = s_vk;
  for (int r = 0; r < 128; ++r) {
    float bv = -3.0e38f;
    int bi = 0x7fffffff;
#pragma unroll
    for (int t = 0; t < 4; ++t) {
      int i = tid + (t << 8);
      float v = vals[i];
      if (v > bv) { bv = v; bi = i; }
    }
    rv[tid] = bv; ri[tid] = bi;
    __syncthreads();
    for (int off = 128; off; off >>= 1) {
      if (tid < off) {
        float ov = rv[tid + off]; int oi = ri[tid + off];
        if (ov > rv[tid] || (ov == rv[tid] && oi < ri[tid])) {
          rv[tid] = ov; ri[tid] = oi;
        }
      }
      __syncthreads();
    }
    if (tid == 0) {
      int wi = ri[0]; float wv = rv[0];
      topi[(size_t)b * 128 + r] = (float)wi;
      if (r < vk && wv > 0.0f) sel[((size_t)b * 128 + r) * NS_ + wi] = 1.0f;
      vals[wi] = -3.0e38f;
    }
    __syncthreads();
  }
}

extern "C" void kernel_launch(void* const* d_in, const int* in_sizes, int n_in,
                              void* d_out, int out_size, void* d_ws, size_t ws_size,
                              hipStream_t stream) {
  (void)in_sizes; (void)n_in; (void)out_size; (void)ws_size;
  const float* x_b = (const float*)d_in[0];
  const float* x_s = (const float*)d_in[1];
  const int* token_types = (const int*)d_in[2];
  const int* base_idxs = (const int*)d_in[3];
  const float* ln1_w = (const float*)d_in[4];
  const float* ln1_b = (const float*)d_in[5];
  const float* ln2_w = (const float*)d_in[6];
  const float* ln2_b = (const float*)d_in[7];
  const float* ln3_w = (const float*)d_in[8];
  const float* ln3_b = (const float*)d_in[9];
  const float* Wq = (const float*)d_in[10];
  const float* Wkv = (const float*)d_in[11];
  const float* es_w1 = (const float*)d_in[12];
  const float* es_b1 = (const float*)d_in[13];
  const float* es_w2 = (const float*)d_in[14];
  const float* es_b2 = (const float*)d_in[15];
  const float* el_w1 = (const float*)d_in[16];
  const float* el_b1 = (const float*)d_in[17];
  const float* el_w2 = (const float*)d_in[18];
  const float* el_b2 = (const float*)d_in[19];
  const float* mlp_w1 = (const float*)d_in[20];
  const float* mlp_b1 = (const float*)d_in[21];
  const float* mlp_w2 = (const float*)d_in[22];
  const float* mlp_b2 = (const float*)d_in[23];

  float* out = (float*)d_out;
  float* sel_out  = out;                 // 8*128*1024
  float* topi_out = out + 1048576;       // 1024
  float* pos_out  = out + 1049600;       // 8192
  float* x_out    = out + 1057792;       // 6291456
  float* kern_out = out + 7349248;       // 6144

  // workspace layout (floats), ~252 MB total
  float* w = (float*)d_ws;
  float* ws0 = w;               // 6291456  : xs_n -> ctx -> x_ln
  float* ws1 = w + 6291456;     // 6291456  : q -> x_norm
  float* ws2 = w + 12582912;    // 25165824 : kv -> {tokens, aw, agg}
  float* ws3 = w + 37748736;    // 25165824 : xb_n -> {scores|partial} -> h
  float* tokens = ws2;                    // 3145728
  float* aw     = ws2 + 3145728;          // 2097152
  float* agg    = ws2 + 5242880;          // 3145728
  float* scores = ws3;                    // 12582912 (1 batch: 6*1024*2048)
  float* part   = ws3 + 12582912;         // 12582912 (16*6*1024*128)
  float* small  = w + 62914560;
  float* maskf  = small;                  // 4096
  float* hasf   = small + 4096;           // 8
  int* cnt      = (int*)(small + 4104);   // 2
  int* perm0    = (int*)(small + 4106);   // 8192
  int* perm1    = (int*)(small + 12298);  // 8192

  const long NSC = (long)NS_ * Cc_;        // 786432
  const long NB2C = (long)NB_ * 2 * Cc_;   // 3145728
  const long SNB = (long)NS_ * NB_;        // 2097152
  const float qk_scale = 0.08838834764831845f;   // 1/sqrt(128)
  const float sc_scale = 0.036084391824351615f;  // 1/sqrt(768)

  hipMemsetAsync(sel_out, 0, (size_t)1048576 * sizeof(float), stream);
  hipMemsetAsync(cnt, 0, 2 * sizeof(int), stream);

  ln_kernel<<<B_ * NS_, 256, 0, stream>>>(x_s, ws0, ln1_w, ln1_b);
  ln_kernel<<<B_ * NB_, 256, 0, stream>>>(x_b, ws3, ln2_w, ln2_b);
  build_perm<<<32, 256, 0, stream>>>(token_types, perm0, perm1, cnt);

  // q = xs_n @ Wq (8192x768x768)
  gemm128<0, 0, false, false><<<dim3(6, 64, 1), 256, 0, stream>>>(
      ws0, Wq, ws1, nullptr, nullptr, nullptr, nullptr,
      8192, 768, 768, 768, 768, 768,
      1, 1, 0, 0, 0, 0, 0, 0, 0, 0, 0, 1.0f);
  // kv = xb_n @ Wkv (16384x1536x768)
  gemm128<0, 0, false, false><<<dim3(12, 128, 1), 256, 0, stream>>>(
      ws3, Wkv, ws2, nullptr, nullptr, nullptr, nullptr,
      16384, 1536, 768, 768, 1536, 1536,
      1, 1, 0, 0, 0, 0, 0, 0, 0, 0, 0, 1.0f);

  // attention: 1 batch per chunk; scores + 16-way split-K PV partials in ws3
  for (int b = 0; b < B_; ++b) {
    const float* qb = ws1 + (size_t)b * NSC;
    const float* kb = ws2 + (size_t)b * NB2C;
    const float* vb = kb + Cc_;
    // QK^T: z = h (6): A off h*128, B off h*128, C off h*SNB
    gemm128<0, 1, false, false><<<dim3(16, 8, 6), 256, 0, stream>>>(
        qb, kb, scores, nullptr, nullptr, nullptr, nullptr,
        1024, 2048, 128, 768, 1536, 2048,
        1, 1, 128, 0, 0, 128, 0, 0, SNB, 0, 0, qk_scale);
    softmax_kernel<8, false><<<6 * 1024, 256, 0, stream>>>(scores, nullptr);
    // PV split-K: z = h*16 + ks (d1=6, d2=16)
    gemm128<0, 0, false, false><<<dim3(1, 8, 96), 256, 0, stream>>>(
        scores, vb, part, nullptr, nullptr, nullptr, nullptr,
        1024, 128, 128, 2048, 1536, 128,
        6, 16, 0, SNB, 128, 0, 128, 128 * 1536, 0, 131072, 786432, 1.0f);
    pv_reduce<<<3072, 256, 0, stream>>>(part, ws0 + (size_t)b * NSC);
  }

  // MoE: per-row single expert. e0 rows=perm0[0..cnt0), e1 rows=perm1
  gemm128<2, 0, true, true><<<dim3(24, 64, 1), 256, 0, stream>>>(
      ws0, es_w1, ws3, es_b1, nullptr, perm0, cnt,
      8192, 3072, 768, 768, 3072, 3072,
      1, 1, 0, 0, 0, 0, 0, 0, 0, 0, 0, 1.0f);
  gemm128<4, 0, false, true><<<dim3(6, 64, 1), 256, 0, stream>>>(
      ws3, es_w2, x_out, es_b2, x_s, perm0, cnt,
      8192, 768, 3072, 3072, 768, 768,
      1, 1, 0, 0, 0, 0, 0, 0, 0, 0, 0, 1.0f);
  gemm128<2, 0, true, true><<<dim3(24, 64, 1), 256, 0, stream>>>(
      ws0, el_w1, ws3, el_b1, nullptr, perm1, cnt + 1,
      8192, 3072, 768, 768, 3072, 3072,
      1, 1, 0, 0, 0, 0, 0, 0, 0, 0, 0, 1.0f);
  gemm128<4, 0, false, true><<<dim3(6, 64, 1), 256, 0, stream>>>(
      ws3, el_w2, x_out, el_b2, x_s, perm1, cnt + 1,
      8192, 768, 3072, 3072, 768, 768,
      1, 1, 0, 0, 0, 0, 0, 0, 0, 0, 0, 1.0f);

  // MLP with residual
  ln_kernel<<<B_ * NS_, 256, 0, stream>>>(x_out, ws0, ln3_w, ln3_b);
  gemm128<2, 0, false, false><<<dim3(24, 64, 1), 256, 0, stream>>>(
      ws0, mlp_w1, ws3, mlp_b1, nullptr, nullptr, nullptr,
      8192, 3072, 768, 768, 3072, 3072,
      1, 1, 0, 0, 0, 0, 0, 0, 0, 0, 0, 1.0f);
  gemm128<3, 0, false, false><<<dim3(6, 64, 1), 256, 0, stream>>>(
      ws3, mlp_w2, x_out, mlp_b2, x_out, nullptr, nullptr,
      8192, 768, 3072, 3072, 768, 768,
      1, 1, 0, 0, 0, 0, 0, 0, 0, 0, 0, 1.0f);

  // x_norm
  rownorm_kernel<<<B_ * NS_, 256, 0, stream>>>(x_out, ws1);

  // token gather + mask
  gather_kernel<<<12288, 256, 0, stream>>>(x_b, base_idxs, tokens, maskf);

  // kernel-attention
  gemm128<0, 1, false, false><<<dim3(4, 4, 8), 256, 0, stream>>>(
      tokens, tokens, aw, nullptr, nullptr, nullptr, nullptr,
      512, 512, 768, 768, 768, 512,
      1, 1, 393216, 0, 0, 393216, 0, 0, 262144, 0, 0, sc_scale);
  softmax_kernel<2, true><<<8 * 512, 256, 0, stream>>>(aw, maskf);
  gemm128<0, 0, false, false><<<dim3(6, 4, 8), 256, 0, stream>>>(
      aw, tokens, agg, nullptr, nullptr, nullptr, nullptr,
      512, 768, 512, 512, 768, 768,
      1, 1, 262144, 0, 0, 393216, 0, 0, 393216, 0, 0, 1.0f);

  kernel_kernel<<<8, 256, 0, stream>>>(agg, maskf, kern_out, hasf);
  pos_kernel<<<B_ * NS_, 256, 0, stream>>>(ws1, kern_out, hasf, pos_out);
  topk_kernel<<<8, 256, 0, stream>>>(pos_out, sel_out, topi_out);
}